// Round 15
// baseline (245.207 us; speedup 1.0000x reference)
//
#include <hip/hip_runtime.h>

#define DEV __device__ __forceinline__

typedef __attribute__((ext_vector_type(8))) short short8;
typedef __bf16 bf16x8 __attribute__((ext_vector_type(8)));
typedef __attribute__((ext_vector_type(4))) float f32x4;

constexpr int NB = 16;
constexpr int NN = 64;
constexpr int ND = 512;
constexpr int NH = 8;

DEV float b2f(unsigned short h) { return __uint_as_float(((unsigned)h) << 16); }
DEV unsigned short f2b(float f) {
    unsigned u = __float_as_uint(f);
    return (unsigned short)((u + 0x7fffu + ((u >> 16) & 1u)) >> 16);
}
// mish(x) = x*(t^2+2t)/(t^2+2t+2), t=e^x; x>15 -> x
DEV float mish_fast(float x) {
    float t = __expf(x);
    float w = t * (t + 2.0f);
    float r = x * w * __builtin_amdgcn_rcpf(w + 2.0f);
    return (x > 15.0f) ? x : r;
}
DEV void gload16(const unsigned short* g, unsigned short* lds) {
    __builtin_amdgcn_global_load_lds((const __attribute__((address_space(1))) void*)g,
                                     (__attribute__((address_space(3))) void*)lds,
                                     16, 0, 0);
}

// ---------------------------------------------------------------------------
__global__ __launch_bounds__(64)
void probe_dtype(const unsigned* __restrict__ adj, int* __restrict__ flag)
{
    int t = threadIdx.x;
    int c = 0;
#pragma unroll
    for (int i = 0; i < 4; ++i) c += (int)((adj[t * 4 + i] >> 15) & 1u);
    for (int off = 32; off; off >>= 1) c += __shfl_xor(c, off);
    if (t == 0) flag[0] = (c > 32) ? 1 : 0;
}

// ---------------------------------------------------------------------------
// Weights -> FRAG-MAJOR bf16: Wt2[(k>>5)*16384 + c*32 + (k&31)] = W[k][c]
// ---------------------------------------------------------------------------
__global__ __launch_bounds__(256)
void wtrans2(const void* W0, const void* W1, const void* W2, const void* W3,
             const void* W4, unsigned short* __restrict__ out,
             const int* __restrict__ flag)
{
    const void* W = (blockIdx.z == 0) ? W0 : (blockIdx.z == 1) ? W1 :
                    (blockIdx.z == 2) ? W2 : (blockIdx.z == 3) ? W3 : W4;
    const int f32 = flag[0];
    unsigned short* o = out + (size_t)blockIdx.z * 262144;
    __shared__ unsigned short tile[64][65];
    const int t = threadIdx.x;
    const int k0 = blockIdx.x * 64, c0 = blockIdx.y * 64;
#pragma unroll
    for (int rep = 0; rep < 16; ++rep) {
        int idx = rep * 256 + t;
        int r = idx >> 6, c = idx & 63;
        size_t gi = (size_t)(k0 + r) * 512 + c0 + c;
        float v = f32 ? ((const float*)W)[gi]
                      : b2f(((const unsigned short*)W)[gi]);
        tile[r][c] = f2b(v);
    }
    __syncthreads();
#pragma unroll
    for (int rep = 0; rep < 16; ++rep) {
        int idx = rep * 256 + t;
        int cc = idx >> 6, kk = idx & 63;
        int k = k0 + kk;
        o[(size_t)(k >> 5) * 16384 + (size_t)(c0 + cc) * 32 + (k & 31)] = tile[kk][cc];
    }
}

// ---------------------------------------------------------------------------
// GEMM v12: inter-PANEL pipelined, multi-source.
// Grid-stride over 32-row x 512-col panels; 512 thr / 8 waves; wave tile
// 32x64 (acc[2][4] = 32 regs -> real headroom at (512,4), 2 blocks/CU).
// Per panel: {issue A(next) global->regs} -> K-loop(buf cur) -> {cvt/scale +
// ds_write next -> buf cur^1} -> ONE barrier -> C(cur) stores (drain under
// next K-loop). Memory streams continuously; 1 barrier per 16 K-steps.
// A-LDS: As[2][32][512], granule slot g^(r&7) (bank-even, r13-proven).
// B: frag-major Wt2, straight global->VGPR (L2-resident; r13-proven).
// Sources: 3 ranges selected per panel (block-uniform -> SGPR).
// PROJ template: raw input (f32 per flag / bf16), bf16 out, no mish.
// !PROJ: bf16 strided input, msg-scale on range 0 only, mish, f32 out.
// In-place safe: panel->block map fixed (panel mod nblocks) -> cross-block
// rows disjoint; in-block: A reads (prefetch) precede that panel's writes.
// ---------------------------------------------------------------------------
struct GSrc {
    const void* A;
    const unsigned short* Bt;
    const void* bias;
    void* out;
    long long apitch;
    long long opitch;
    int npanels;
};

template<bool PROJ>
__global__ __launch_bounds__(512, 4)
void gemm12(GSrc s0, GSrc s1, GSrc s2,
            const float* __restrict__ msg,
            const int* __restrict__ flag, int nblocks)
{
    __shared__ alignas(16) unsigned short As[2][32][512];   // 64 KB
    const int f32g = flag[0];
    const int totp = s0.npanels + s1.npanels + s2.npanels;
    const int t = threadIdx.x;
    const int lane = t & 63;
    const int wv = t >> 6;           // 0..7 = 64-col panel
    const int rA = lane & 15;
    const int p  = lane >> 4;
    // staging coords: row 0..31, chunk 0..15 (32 elems each)
    const int sr = t >> 4;
    const int sq = t & 15;

    int pc = blockIdx.x;
    if (pc >= totp) return;

    GSrc gc, gn;
    long long rc = 0, rn = 0;
    bool uc = false, un = false;

    auto selectSrc = [&](int pp, GSrc& g, long long& prow, bool& umsg) {
        if (pp < s0.npanels) { g = s0; prow = (long long)pp * 32; umsg = !PROJ; }
        else if (pp < s0.npanels + s1.npanels) {
            g = s1; prow = (long long)(pp - s0.npanels) * 32; umsg = false;
        } else {
            g = s2; prow = (long long)(pp - s0.npanels - s1.npanels) * 32; umsg = false;
        }
    };

    f32x4 pf[8];      // f32 prefetch (PROJ f32 path)
    short8 ph[4];     // bf16 prefetch
    float pscale = 1.0f;

    auto loadPanel = [&](const GSrc& g, long long prow, bool umsg) {
        long long gr = prow + sr;
        if (PROJ && f32g) {
            const float* src = (const float*)g.A + gr * g.apitch + sq * 32;
#pragma unroll
            for (int i = 0; i < 8; ++i)
                pf[i] = *reinterpret_cast<const f32x4*>(src + i * 4);
        } else {
            const unsigned short* src = (const unsigned short*)g.A + gr * g.apitch + sq * 32;
#pragma unroll
            for (int i = 0; i < 4; ++i)
                ph[i] = *reinterpret_cast<const short8*>(src + i * 8);
            if (!PROJ) {
                if (umsg) {
                    int b = (int)(gr >> 12), m = (int)(gr >> 6) & 63, n = (int)gr & 63;
                    pscale = msg[(((long long)b * 8 + (sq >> 1)) << 12) + m * 64 + n];
                } else {
                    pscale = 1.0f;
                }
            }
        }
    };

    auto writePanel = [&](int buf) {
        short8 sv[4];
        if (PROJ && f32g) {
#pragma unroll
            for (int i = 0; i < 4; ++i) {
#pragma unroll
                for (int j = 0; j < 4; ++j) {
                    sv[i][j]     = (short)f2b(pf[2 * i][j]);
                    sv[i][j + 4] = (short)f2b(pf[2 * i + 1][j]);
                }
            }
        } else {
#pragma unroll
            for (int i = 0; i < 4; ++i) {
                sv[i] = ph[i];
                if (!PROJ) {
#pragma unroll
                    for (int j = 0; j < 8; ++j)
                        sv[i][j] = (short)f2b(b2f((unsigned short)sv[i][j]) * pscale);
                }
            }
        }
#pragma unroll
        for (int i = 0; i < 4; ++i) {
            int g = sq * 4 + i;
            *reinterpret_cast<short8*>(&As[buf][sr][(g ^ (sr & 7)) * 8]) = sv[i];
        }
    };

    // ---- prologue: stage panel pc into buf 0 ----
    selectSrc(pc, gc, rc, uc);
    loadPanel(gc, rc, uc);
    writePanel(0);
    __syncthreads();
    int cur = 0;

    for (;;) {
        const int pn = pc + nblocks;
        const bool have_next = pn < totp;
        if (have_next) { selectSrc(pn, gn, rn, un); loadPanel(gn, rn, un); }

        f32x4 acc[2][4];
#pragma unroll
        for (int mi = 0; mi < 2; ++mi)
#pragma unroll
            for (int ni = 0; ni < 4; ++ni) acc[mi][ni] = f32x4{0.f, 0.f, 0.f, 0.f};

        // ---- K-loop on buf[cur]; B straight from L2 (frag-major) ----
        const unsigned short* bbase = gc.Bt + ((size_t)(wv * 64 + rA) * 32 + p * 8);
#pragma unroll
        for (int s = 0; s < 16; ++s) {
            bf16x8 bf[4], af[2];
#pragma unroll
            for (int ni = 0; ni < 4; ++ni)
                bf[ni] = *reinterpret_cast<const bf16x8*>(
                    bbase + (size_t)s * 16384 + ni * 512);
#pragma unroll
            for (int mi = 0; mi < 2; ++mi) {
                int r = mi * 16 + rA;
                af[mi] = *reinterpret_cast<const bf16x8*>(
                    &As[cur][r][((s * 4 + p) ^ (r & 7)) * 8]);
            }
#pragma unroll
            for (int mi = 0; mi < 2; ++mi)
#pragma unroll
                for (int ni = 0; ni < 4; ++ni)
                    acc[mi][ni] = __builtin_amdgcn_mfma_f32_16x16x32_bf16(
                        af[mi], bf[ni], acc[mi][ni], 0, 0, 0);
        }

        if (have_next) {
            writePanel(cur ^ 1);     // waits prefetch loads; writes OTHER buf
            __syncthreads();         // publish; one barrier per panel
        }

        // ---- epilogue: C/D col=lane&15, row=(lane>>4)*4+rr ----
        {
            const int orow_q = (lane >> 4) * 4;
#pragma unroll
            for (int mi = 0; mi < 2; ++mi) {
#pragma unroll
                for (int ni = 0; ni < 4; ++ni) {
                    int col = wv * 64 + ni * 16 + rA;
                    float bz = f32g ? ((const float*)gc.bias)[col]
                                    : b2f(((const unsigned short*)gc.bias)[col]);
                    long long rbase = rc + mi * 16 + orow_q;
#pragma unroll
                    for (int rr = 0; rr < 4; ++rr) {
                        float v = acc[mi][ni][rr] + bz;
                        if (!PROJ) v = mish_fast(v);
                        long long oi = (rbase + rr) * gc.opitch + col;
                        if (!PROJ) ((float*)gc.out)[oi] = v;
                        else       ((unsigned short*)gc.out)[oi] = f2b(v);
                    }
                }
            }
        }

        if (!have_next) break;
        pc = pn; gc = gn; rc = rn; uc = un; cur ^= 1;
    }
}

// ---------------------------------------------------------------------------
// Pass A: raw scores, kp read EXACTLY ONCE (verified rounds 6-14).
// ---------------------------------------------------------------------------
__global__ __launch_bounds__(256)
void score_kernel(const unsigned short* __restrict__ q,
                  const unsigned short* __restrict__ kp,
                  float* __restrict__ outS,
                  float* __restrict__ inS)
{
    const int bid = blockIdx.x;            // 512 blocks
    const int b  = bid >> 5;
    const int i0 = ((bid >> 2) & 7) * 8;
    const int j0 = (bid & 3) * 16;
    const int t = threadIdx.x, lane = t & 63, wv = t >> 6;

    __shared__ alignas(16) unsigned short qs[24][512];
    __shared__ float souts[8][16][8];
    __shared__ float sins[16][8][8];

#pragma unroll
    for (int r8 = 0; r8 < 6; ++r8) {
        int r = wv * 6 + r8;
        int grow = (r < 8) ? (i0 + r) : (j0 + r - 8);
        gload16(q + ((long long)(b * 64 + grow)) * 512 + lane * 8, &qs[r][0]);
    }
    __syncthreads();

    for (int batch = 0; batch < 4; ++batch) {
        const int rbase = wv * 32 + batch * 8;
        short8 kv[8];
#pragma unroll
        for (int u = 0; u < 8; ++u) {
            int r = rbase + u;
            int ii = r >> 4, jj = r & 15;
            kv[u] = *reinterpret_cast<const short8*>(
                kp + ((long long)((b * 64 + i0 + ii) * 64) + j0 + jj) * 1024 + lane * 8);
        }
#pragma unroll
        for (int u = 0; u < 8; ++u) {
            int r = rbase + u;
            int ii = r >> 4, jj = r & 15;
            short8 qi = *reinterpret_cast<const short8*>(&qs[ii][lane * 8]);
            short8 qj = *reinterpret_cast<const short8*>(&qs[8 + jj][lane * 8]);
            float so = 0.f, si = 0.f;
#pragma unroll
            for (int e = 0; e < 8; ++e) {
                float kf = b2f((unsigned short)kv[u][e]);
                so += kf * b2f((unsigned short)qi[e]);
                si += kf * b2f((unsigned short)qj[e]);
            }
#pragma unroll
            for (int off = 1; off < 8; off <<= 1) {
                so += __shfl_xor(so, off);
                si += __shfl_xor(si, off);
            }
            if ((lane & 7) == 0) {
                souts[ii][jj][lane >> 3] = so * 0.125f;
                sins[jj][ii][lane >> 3]  = si * 0.125f;
            }
        }
    }
    __syncthreads();

    {
        int h  = t >> 5;
        int ii = (t >> 2) & 7;
        int qq = t & 3;
        f32x4 v;
#pragma unroll
        for (int e = 0; e < 4; ++e) v[e] = souts[ii][qq * 4 + e][h];
        *reinterpret_cast<f32x4*>(
            &outS[(((long long)(b * 8 + h) * 64) + i0 + ii) * 64 + j0 + qq * 4]) = v;
    }
    {
        int h  = t >> 5;
        int jj = (t >> 1) & 15;
        int hf = t & 1;
        f32x4 v;
#pragma unroll
        for (int e = 0; e < 4; ++e) v[e] = sins[jj][hf * 4 + e][h];
        *reinterpret_cast<f32x4*>(
            &inS[(((long long)(b * 8 + h) * 64) + j0 + jj) * 64 + i0 + hf * 4]) = v;
    }
}

// ---------------------------------------------------------------------------
__global__ __launch_bounds__(256)
void softmax_combine(float* __restrict__ outS, const float* __restrict__ inS)
{
    const long long row = (long long)blockIdx.x * 4 + (threadIdx.x >> 6);
    const int l = threadIdx.x & 63;
    const int x = (int)(row & 63);
    float so = outS[row * 64 + l];
    float si = inS[row * 64 + l];
    float mo = so, mi = si;
    for (int off = 32; off; off >>= 1) {
        mo = fmaxf(mo, __shfl_xor(mo, off));
        mi = fmaxf(mi, __shfl_xor(mi, off));
    }
    float eo = __expf(so - mo), ei = __expf(si - mi);
    float zo = eo, zi = ei;
    for (int off = 32; off; off >>= 1) {
        zo += __shfl_xor(zo, off);
        zi += __shfl_xor(zi, off);
    }
    float ao = eo / zo, ai = ei / zi;
    outS[row * 64 + l] = (l == x) ? ai : (ao + ai);
}

// ---------------------------------------------------------------------------
__global__ __launch_bounds__(512)
void nh_kernel(const float* __restrict__ msg,
               const unsigned short* __restrict__ v,
               unsigned short* __restrict__ nh)
{
    const int bm = blockIdx.x;
    const int b = bm >> 6, m = bm & 63;
    const int t = threadIdx.x;
    __shared__ float ms2[8 * 64];
    ms2[t] = msg[((long long)b * 8 + (t >> 6)) * 4096 + m * 64 + (t & 63)];
    __syncthreads();
    const float* mrow = &ms2[(t >> 6) * 64];
    float acc = 0.f;
#pragma unroll 8
    for (int n = 0; n < 64; ++n)
        acc += mrow[n] * b2f(v[((long long)b * 64 + n) * 512 + t]);
    nh[(long long)bm * 1024 + t] = f2b(acc);
}

// ---------------------------------------------------------------------------
extern "C" void kernel_launch(void* const* d_in, const int* in_sizes, int n_in,
                              void* d_out, int out_size, void* d_ws, size_t ws_size,
                              hipStream_t stream)
{
    const void* qn = d_in[0];
    const void* vn = d_in[1];
    const void* ke = d_in[2];
    const unsigned* adj = (const unsigned*)d_in[3];
    const void* Wq = d_in[4];  const void* bq = d_in[5];
    const void* Wk = d_in[6];  const void* bk = d_in[7];
    const void* Wv = d_in[8];  const void* bv = d_in[9];
    const void* Wn = d_in[10]; const void* bn = d_in[11];
    const void* We = d_in[12]; const void* be = d_in[13];

    float* out_node = (float*)d_out;                       // 16*64*512 f32 (2 MB)
    float* out_edge = out_node + (size_t)NB * NN * ND;     // 16*64*64*512 f32
    unsigned short* kp = (unsigned short*)out_edge;        // bf16, pitch 1024 shorts
    unsigned short* nh = (unsigned short*)out_node;        // bf16, pitch 1024 shorts
    float* inS = out_node;  // in-scores scratch (2 MB) — dead before nh_kernel

    char* wsb = (char*)d_ws;
    int* flag = (int*)wsb;
    unsigned short* Wt  = (unsigned short*)(wsb + 16);     // 5 x 512 KB (frag-major)
    unsigned short* Wqt = Wt + 0 * 262144;
    unsigned short* Wkt = Wt + 1 * 262144;
    unsigned short* Wvt = Wt + 2 * 262144;
    unsigned short* Wnt = Wt + 3 * 262144;
    unsigned short* Wet = Wt + 4 * 262144;
    unsigned short* q_ws = Wt + 5 * 262144;                // 1 MB bf16
    unsigned short* v_ws = q_ws + 524288;                  // 1 MB bf16
    float* msg = (float*)(v_ws + 524288);                  // 2 MB f32
    // ws total ~6.5 MB

    probe_dtype<<<1, 64, 0, stream>>>(adj, flag);
    wtrans2<<<dim3(8, 8, 5), 256, 0, stream>>>(Wq, Wk, Wv, Wn, We, Wt, flag);

    // PROJ dispatch: ke->kp (2048 panels) + q (32) + v (32), panel-pipelined
    {
        GSrc sk{ke, Wkt, bk, kp,   512, 1024, 2048};
        GSrc sq{qn, Wqt, bq, q_ws, 512,  512,   32};
        GSrc sv{vn, Wvt, bv, v_ws, 512,  512,   32};
        gemm12<true><<<512, 512, 0, stream>>>(sk, sq, sv, nullptr, flag, 512);
    }
    // message: raw scores (kp read once) + softmax/combine
    score_kernel<<<512, 256, 0, stream>>>(q_ws, kp, msg, inS);
    softmax_combine<<<2048, 256, 0, stream>>>(msg, inS);
    // node hidden
    nh_kernel<<<NB * NN, 512, 0, stream>>>(msg, v_ws, nh);
    // OUT dispatch: edge (msg-scale, 2048 panels) + node (32 panels), in-place
    {
        GSrc se{kp, Wet, be, out_edge, 1024, 512, 2048};
        GSrc sn{nh, Wnt, bn, out_node, 1024, 512,   32};
        GSrc sz{nullptr, nullptr, nullptr, nullptr, 0, 0, 0};
        gemm12<false><<<512, 512, 0, stream>>>(se, sn, sz, msg, flag, 512);
    }
}

// Round 16
// 195.484 us; speedup vs baseline: 1.2544x; 1.2544x over previous
//
#include <hip/hip_runtime.h>

#define DEV __device__ __forceinline__

typedef __attribute__((ext_vector_type(8))) short short8;
typedef __bf16 bf16x8 __attribute__((ext_vector_type(8)));
typedef __attribute__((ext_vector_type(4))) float f32x4;

constexpr int NB = 16;
constexpr int NN = 64;
constexpr int ND = 512;
constexpr int NH = 8;

DEV float b2f(unsigned short h) { return __uint_as_float(((unsigned)h) << 16); }
DEV unsigned short f2b(float f) {
    unsigned u = __float_as_uint(f);
    return (unsigned short)((u + 0x7fffu + ((u >> 16) & 1u)) >> 16);
}
// mish(x) = x*(t^2+2t)/(t^2+2t+2), t=e^x; x>15 -> x
DEV float mish_fast(float x) {
    float t = __expf(x);
    float w = t * (t + 2.0f);
    float r = x * w * __builtin_amdgcn_rcpf(w + 2.0f);
    return (x > 15.0f) ? x : r;
}
DEV void gload16(const unsigned short* g, unsigned short* lds) {
    __builtin_amdgcn_global_load_lds((const __attribute__((address_space(1))) void*)g,
                                     (__attribute__((address_space(3))) void*)lds,
                                     16, 0, 0);
}

// ---------------------------------------------------------------------------
__global__ __launch_bounds__(64)
void probe_dtype(const unsigned* __restrict__ adj, int* __restrict__ flag)
{
    int t = threadIdx.x;
    int c = 0;
#pragma unroll
    for (int i = 0; i < 4; ++i) c += (int)((adj[t * 4 + i] >> 15) & 1u);
    for (int off = 32; off; off >>= 1) c += __shfl_xor(c, off);
    if (t == 0) flag[0] = (c > 32) ? 1 : 0;
}

// ---------------------------------------------------------------------------
// Weights -> FRAG-MAJOR bf16: Wt2[(k>>5)*16384 + c*32 + (k&31)] = W[k][c]
// (a wave's B-fragment = one contiguous 1 KB load)
// ---------------------------------------------------------------------------
__global__ __launch_bounds__(256)
void wtrans2(const void* W0, const void* W1, const void* W2, const void* W3,
             const void* W4, unsigned short* __restrict__ out,
             const int* __restrict__ flag)
{
    const void* W = (blockIdx.z == 0) ? W0 : (blockIdx.z == 1) ? W1 :
                    (blockIdx.z == 2) ? W2 : (blockIdx.z == 3) ? W3 : W4;
    const int f32 = flag[0];
    unsigned short* o = out + (size_t)blockIdx.z * 262144;
    __shared__ unsigned short tile[64][65];
    const int t = threadIdx.x;
    const int k0 = blockIdx.x * 64, c0 = blockIdx.y * 64;
#pragma unroll
    for (int rep = 0; rep < 16; ++rep) {
        int idx = rep * 256 + t;
        int r = idx >> 6, c = idx & 63;
        size_t gi = (size_t)(k0 + r) * 512 + c0 + c;
        float v = f32 ? ((const float*)W)[gi]
                      : b2f(((const unsigned short*)W)[gi]);
        tile[r][c] = f2b(v);
    }
    __syncthreads();
#pragma unroll
    for (int rep = 0; rep < 16; ++rep) {
        int idx = rep * 256 + t;
        int cc = idx >> 6, kk = idx & 63;
        int k = k0 + kk;
        o[(size_t)(k >> 5) * 16384 + (size_t)(c0 + cc) * 32 + (k & 31)] = tile[kk][cc];
    }
}

// ---------------------------------------------------------------------------
// GEMM v13 = r13's gemm10 + explicit depth-1 B-register prefetch + setprio.
// out[64 x 512 per block] = f( A[64 x 512] @ W + bias ).
// - A staged ONCE into 64 KB LDS (bf16, granule slot g^(r&7); frag reads
//   2-way bank-aliased = free). f32 cvt / msg-scale folded into staging.
//   ONE __syncthreads() total.
// - B read straight global->VGPR from frag-major Wt2: per wave-step, 4
//   contiguous 1 KB loads. Explicit ping-pong bfA/bfB (manual even/odd
//   unroll, static indexing per rule #20): B(s+1) issues BEFORE step s's
//   MFMA cluster -> one full step (~310 cyc MFMA) of latency tolerance.
//   r13's compiler used only 60/128 VGPRs and did NOT pipeline; this forces
//   it.  launch_bounds(512,3): 170-reg budget (acc64+af16+bfA16+bfB16+addr
//   ~145, no spill -- r9 sentinel: WRITE_SIZE must stay ~66 MB).
// - setprio(1) around MFMA clusters (T5: free-drifting waves regime).
// 512 thr / 8 waves, wave tile 64x64 (acc[4][4]).
// AMODE: 0 = raw input (f32 per flag / bf16), 1 = bf16, 2 = bf16 * msg.
// In-place safe: ALL global A reads precede the staging barrier; writes
// after the K-loop; blocks own disjoint 64-row ranges.
// ---------------------------------------------------------------------------
template<int AMODE, bool MISH, bool OUTF32>
__global__ __launch_bounds__(512, 3)
void gemm13(const void* A, long long apitch,
            const unsigned short* __restrict__ Bt2,
            const void* __restrict__ bias_raw,
            const float* __restrict__ msg,
            void* out, long long opitch,
            const int* __restrict__ flag,
            const void* A2, const unsigned short* Bt2b,
            const void* bias2, void* out2)
{
    __shared__ alignas(16) unsigned short As[64][512];   // 64 KB
    const int f32g = flag[0];
    const int t = threadIdx.x;
    const int lane = t & 63;
    const int wv = t >> 6;           // 0..7 = 64-col panel

    long long row0;
    const void* Ap = A; const unsigned short* Btp = Bt2;
    const void* biasp = bias_raw; void* outp = out;
    if (A2 != nullptr && (int)blockIdx.x >= (int)(gridDim.x >> 1)) {
        Ap = A2; Btp = Bt2b; biasp = bias2; outp = out2;
        row0 = (long long)(blockIdx.x - (gridDim.x >> 1)) * 64;
    } else {
        row0 = (long long)blockIdx.x * 64;
    }

    // ---- stage the whole A panel once (64 rows x 512 k, swizzled bf16) ----
    {
        const int r = t >> 3;            // row 0..63
        const int q = t & 7;             // granule phase 0..7
        const long long gr = row0 + r;
        const float* mrow = nullptr;
        if (AMODE == 2) {
            int b = (int)(gr >> 12), m = (int)(gr >> 6) & 63, n = (int)gr & 63;
            mrow = msg + (((long long)b * 8) * 64 + m) * 64 + n;   // + head*4096
        }
        if (AMODE == 0 && f32g) {
            const float* Af = (const float*)Ap + gr * apitch;
#pragma unroll
            for (int i = 0; i < 8; ++i) {
                int g = q + 8 * i;       // granule 0..63; head = i
                f32x4 x0 = *reinterpret_cast<const f32x4*>(Af + g * 8);
                f32x4 x1 = *reinterpret_cast<const f32x4*>(Af + g * 8 + 4);
                short8 sv;
#pragma unroll
                for (int j = 0; j < 4; ++j) {
                    sv[j]     = (short)f2b(x0[j]);
                    sv[j + 4] = (short)f2b(x1[j]);
                }
                *reinterpret_cast<short8*>(&As[r][(g ^ (r & 7)) * 8]) = sv;
            }
        } else {
            const unsigned short* Ah = (const unsigned short*)Ap + gr * apitch;
#pragma unroll
            for (int i = 0; i < 8; ++i) {
                int g = q + 8 * i;
                short8 v = *reinterpret_cast<const short8*>(Ah + g * 8);
                if (AMODE == 2) {
                    float sc = mrow[i * 4096];          // head = i
#pragma unroll
                    for (int j = 0; j < 8; ++j)
                        v[j] = (short)f2b(b2f((unsigned short)v[j]) * sc);
                }
                *reinterpret_cast<short8*>(&As[r][(g ^ (r & 7)) * 8]) = v;
            }
        }
    }
    __syncthreads();      // the ONLY synchronization in this kernel

    const int rA = lane & 15;
    const int p  = lane >> 4;
    // frag-major B: wave wv, frag ni, step s -> 1 KB contiguous at
    //   Btp + s*16384 + (wv*64 + ni*16)*32 + rA*32 + p*8
    const unsigned short* bbase = Btp + ((size_t)(wv * 64 + rA) * 32 + p * 8);

    f32x4 acc[4][4];
#pragma unroll
    for (int mi = 0; mi < 4; ++mi)
#pragma unroll
        for (int ni = 0; ni < 4; ++ni) acc[mi][ni] = f32x4{0.f, 0.f, 0.f, 0.f};

    // ---- K-loop: 16 steps, barrier-free, explicit B ping-pong prefetch ----
    bf16x8 bfA[4], bfB[4];
#pragma unroll
    for (int ni = 0; ni < 4; ++ni)
        bfA[ni] = *reinterpret_cast<const bf16x8*>(bbase + (size_t)0 + ni * 512);

#pragma unroll
    for (int s2 = 0; s2 < 8; ++s2) {
        const int s = 2 * s2;
        // prefetch B(s+1) before consuming B(s)
#pragma unroll
        for (int ni = 0; ni < 4; ++ni)
            bfB[ni] = *reinterpret_cast<const bf16x8*>(
                bbase + (size_t)(s + 1) * 16384 + ni * 512);
        {
            bf16x8 af[4];
#pragma unroll
            for (int mi = 0; mi < 4; ++mi)
                af[mi] = *reinterpret_cast<const bf16x8*>(
                    &As[mi * 16 + rA][((s * 4 + p) ^ (rA & 7)) * 8]);
            __builtin_amdgcn_s_setprio(1);
#pragma unroll
            for (int mi = 0; mi < 4; ++mi)
#pragma unroll
                for (int ni = 0; ni < 4; ++ni)
                    acc[mi][ni] = __builtin_amdgcn_mfma_f32_16x16x32_bf16(
                        af[mi], bfA[ni], acc[mi][ni], 0, 0, 0);
            __builtin_amdgcn_s_setprio(0);
        }
        // prefetch B(s+2) before consuming B(s+1)
        if (s2 < 7) {
#pragma unroll
            for (int ni = 0; ni < 4; ++ni)
                bfA[ni] = *reinterpret_cast<const bf16x8*>(
                    bbase + (size_t)(s + 2) * 16384 + ni * 512);
        }
        {
            bf16x8 af[4];
#pragma unroll
            for (int mi = 0; mi < 4; ++mi)
                af[mi] = *reinterpret_cast<const bf16x8*>(
                    &As[mi * 16 + rA][(((s + 1) * 4 + p) ^ (rA & 7)) * 8]);
            __builtin_amdgcn_s_setprio(1);
#pragma unroll
            for (int mi = 0; mi < 4; ++mi)
#pragma unroll
                for (int ni = 0; ni < 4; ++ni)
                    acc[mi][ni] = __builtin_amdgcn_mfma_f32_16x16x32_bf16(
                        af[mi], bfB[ni], acc[mi][ni], 0, 0, 0);
            __builtin_amdgcn_s_setprio(0);
        }
    }

    // ---- epilogue: C/D layout col=lane&15, row=(lane>>4)*4+rr ----
    const int orow_q = (lane >> 4) * 4;
#pragma unroll
    for (int mi = 0; mi < 4; ++mi) {
#pragma unroll
        for (int ni = 0; ni < 4; ++ni) {
            int col = wv * 64 + ni * 16 + rA;
            float bz = f32g ? ((const float*)biasp)[col]
                            : b2f(((const unsigned short*)biasp)[col]);
            long long rbase = row0 + mi * 16 + orow_q;
#pragma unroll
            for (int rr = 0; rr < 4; ++rr) {
                float v = acc[mi][ni][rr] + bz;
                if (MISH) v = mish_fast(v);
                long long oi = (rbase + rr) * opitch + col;
                if (OUTF32) ((float*)outp)[oi] = v;
                else        ((unsigned short*)outp)[oi] = f2b(v);
            }
        }
    }
}

// ---------------------------------------------------------------------------
// Pass A: raw scores, kp read EXACTLY ONCE (verified rounds 6-15).
// ---------------------------------------------------------------------------
__global__ __launch_bounds__(256)
void score_kernel(const unsigned short* __restrict__ q,
                  const unsigned short* __restrict__ kp,
                  float* __restrict__ outS,
                  float* __restrict__ inS)
{
    const int bid = blockIdx.x;            // 512 blocks
    const int b  = bid >> 5;
    const int i0 = ((bid >> 2) & 7) * 8;
    const int j0 = (bid & 3) * 16;
    const int t = threadIdx.x, lane = t & 63, wv = t >> 6;

    __shared__ alignas(16) unsigned short qs[24][512];
    __shared__ float souts[8][16][8];
    __shared__ float sins[16][8][8];

#pragma unroll
    for (int r8 = 0; r8 < 6; ++r8) {
        int r = wv * 6 + r8;
        int grow = (r < 8) ? (i0 + r) : (j0 + r - 8);
        gload16(q + ((long long)(b * 64 + grow)) * 512 + lane * 8, &qs[r][0]);
    }
    __syncthreads();

    for (int batch = 0; batch < 4; ++batch) {
        const int rbase = wv * 32 + batch * 8;
        short8 kv[8];
#pragma unroll
        for (int u = 0; u < 8; ++u) {
            int r = rbase + u;
            int ii = r >> 4, jj = r & 15;
            kv[u] = *reinterpret_cast<const short8*>(
                kp + ((long long)((b * 64 + i0 + ii) * 64) + j0 + jj) * 1024 + lane * 8);
        }
#pragma unroll
        for (int u = 0; u < 8; ++u) {
            int r = rbase + u;
            int ii = r >> 4, jj = r & 15;
            short8 qi = *reinterpret_cast<const short8*>(&qs[ii][lane * 8]);
            short8 qj = *reinterpret_cast<const short8*>(&qs[8 + jj][lane * 8]);
            float so = 0.f, si = 0.f;
#pragma unroll
            for (int e = 0; e < 8; ++e) {
                float kf = b2f((unsigned short)kv[u][e]);
                so += kf * b2f((unsigned short)qi[e]);
                si += kf * b2f((unsigned short)qj[e]);
            }
#pragma unroll
            for (int off = 1; off < 8; off <<= 1) {
                so += __shfl_xor(so, off);
                si += __shfl_xor(si, off);
            }
            if ((lane & 7) == 0) {
                souts[ii][jj][lane >> 3] = so * 0.125f;
                sins[jj][ii][lane >> 3]  = si * 0.125f;
            }
        }
    }
    __syncthreads();

    {
        int h  = t >> 5;
        int ii = (t >> 2) & 7;
        int qq = t & 3;
        f32x4 v;
#pragma unroll
        for (int e = 0; e < 4; ++e) v[e] = souts[ii][qq * 4 + e][h];
        *reinterpret_cast<f32x4*>(
            &outS[(((long long)(b * 8 + h) * 64) + i0 + ii) * 64 + j0 + qq * 4]) = v;
    }
    {
        int h  = t >> 5;
        int jj = (t >> 1) & 15;
        int hf = t & 1;
        f32x4 v;
#pragma unroll
        for (int e = 0; e < 4; ++e) v[e] = sins[jj][hf * 4 + e][h];
        *reinterpret_cast<f32x4*>(
            &inS[(((long long)(b * 8 + h) * 64) + j0 + jj) * 64 + i0 + hf * 4]) = v;
    }
}

// ---------------------------------------------------------------------------
__global__ __launch_bounds__(256)
void softmax_combine(float* __restrict__ outS, const float* __restrict__ inS)
{
    const long long row = (long long)blockIdx.x * 4 + (threadIdx.x >> 6);
    const int l = threadIdx.x & 63;
    const int x = (int)(row & 63);
    float so = outS[row * 64 + l];
    float si = inS[row * 64 + l];
    float mo = so, mi = si;
    for (int off = 32; off; off >>= 1) {
        mo = fmaxf(mo, __shfl_xor(mo, off));
        mi = fmaxf(mi, __shfl_xor(mi, off));
    }
    float eo = __expf(so - mo), ei = __expf(si - mi);
    float zo = eo, zi = ei;
    for (int off = 32; off; off >>= 1) {
        zo += __shfl_xor(zo, off);
        zi += __shfl_xor(zi, off);
    }
    float ao = eo / zo, ai = ei / zi;
    outS[row * 64 + l] = (l == x) ? ai : (ao + ai);
}

// ---------------------------------------------------------------------------
__global__ __launch_bounds__(512)
void nh_kernel(const float* __restrict__ msg,
               const unsigned short* __restrict__ v,
               unsigned short* __restrict__ nh)
{
    const int bm = blockIdx.x;
    const int b = bm >> 6, m = bm & 63;
    const int t = threadIdx.x;
    __shared__ float ms2[8 * 64];
    ms2[t] = msg[((long long)b * 8 + (t >> 6)) * 4096 + m * 64 + (t & 63)];
    __syncthreads();
    const float* mrow = &ms2[(t >> 6) * 64];
    float acc = 0.f;
#pragma unroll 8
    for (int n = 0; n < 64; ++n)
        acc += mrow[n] * b2f(v[((long long)b * 64 + n) * 512 + t]);
    nh[(long long)bm * 1024 + t] = f2b(acc);
}

// ---------------------------------------------------------------------------
extern "C" void kernel_launch(void* const* d_in, const int* in_sizes, int n_in,
                              void* d_out, int out_size, void* d_ws, size_t ws_size,
                              hipStream_t stream)
{
    const void* qn = d_in[0];
    const void* vn = d_in[1];
    const void* ke = d_in[2];
    const unsigned* adj = (const unsigned*)d_in[3];
    const void* Wq = d_in[4];  const void* bq = d_in[5];
    const void* Wk = d_in[6];  const void* bk = d_in[7];
    const void* Wv = d_in[8];  const void* bv = d_in[9];
    const void* Wn = d_in[10]; const void* bn = d_in[11];
    const void* We = d_in[12]; const void* be = d_in[13];

    float* out_node = (float*)d_out;                       // 16*64*512 f32 (2 MB)
    float* out_edge = out_node + (size_t)NB * NN * ND;     // 16*64*64*512 f32
    unsigned short* kp = (unsigned short*)out_edge;        // bf16, pitch 1024 shorts
    unsigned short* nh = (unsigned short*)out_node;        // bf16, pitch 1024 shorts
    float* inS = out_node;  // in-scores scratch (2 MB) — dead before nh_kernel

    char* wsb = (char*)d_ws;
    int* flag = (int*)wsb;
    unsigned short* Wt  = (unsigned short*)(wsb + 16);     // 5 x 512 KB (frag-major)
    unsigned short* Wqt = Wt + 0 * 262144;
    unsigned short* Wkt = Wt + 1 * 262144;
    unsigned short* Wvt = Wt + 2 * 262144;
    unsigned short* Wnt = Wt + 3 * 262144;
    unsigned short* Wet = Wt + 4 * 262144;
    unsigned short* q_ws = Wt + 5 * 262144;                // 1 MB bf16
    unsigned short* v_ws = q_ws + 524288;                  // 1 MB bf16
    float* msg = (float*)(v_ws + 524288);                  // 2 MB f32
    // ws total ~6.5 MB

    probe_dtype<<<1, 64, 0, stream>>>(adj, flag);
    wtrans2<<<dim3(8, 8, 5), 256, 0, stream>>>(Wq, Wk, Wv, Wn, We, Wt, flag);
    // q + v projections merged (f32 A): blocks 0-15 -> q, 16-31 -> v
    gemm13<0, false, false><<<32, 512, 0, stream>>>(
        qn, 512, Wqt, bq, nullptr, q_ws, 512, flag, vn, Wvt, bv, v_ws);
    // k projection -> strided bf16 inside the edge f32 output region
    gemm13<0, false, false><<<1024, 512, 0, stream>>>(
        ke, 512, Wkt, bk, nullptr, kp, 1024, flag, nullptr, nullptr, nullptr, nullptr);
    // message: raw scores (kp read once) + softmax/combine
    score_kernel<<<512, 256, 0, stream>>>(q_ws, kp, msg, inS);
    softmax_combine<<<2048, 256, 0, stream>>>(msg, inS);
    // node path
    nh_kernel<<<NB * NN, 512, 0, stream>>>(msg, v_ws, nh);
    gemm13<1, true, true><<<16, 512, 0, stream>>>(
        nh, 1024, Wnt, bn, nullptr, out_node, 512, flag, nullptr, nullptr, nullptr, nullptr);
    // edge path: msg-scaling fused into A-staging; in-place
    gemm13<2, true, true><<<1024, 512, 0, stream>>>(
        kp, 1024, Wet, be, msg, out_edge, 512, flag, nullptr, nullptr, nullptr, nullptr);
}